// Round 12
// baseline (222.982 us; speedup 1.0000x reference)
//
#include <hip/hip_runtime.h>
#include <math.h>

typedef int intx4 __attribute__((ext_vector_type(4)));
typedef int intx8 __attribute__((ext_vector_type(8)));
typedef float floatx16 __attribute__((ext_vector_type(16)));

#define N_ROWS 8192
#define KDIM 1024

// E8M0 scale bytes: 123 -> 2^-4 per side (data pre-scaled by 2^4 each side)
#define SCALE_WORD 0x7B7B7B7B

// order-preserving float->int encoding for atomicMax
__device__ __forceinline__ int fenc(float f) {
  int i = __float_as_int(f);
  return i >= 0 ? i : (i ^ 0x7fffffff);
}
__device__ __forceinline__ float fdec(int e) {
  int b = e >= 0 ? e : (e ^ 0x7fffffff);
  return __int_as_float(b);
}

// async 16B global->LDS DMA (m97 pattern: per-lane global src, LDS dest must
// equal wave-uniform base + lane*16 -- ours does by construction).
__device__ __forceinline__ void gld_lds16(const void* g, void* l) {
  __builtin_amdgcn_global_load_lds(
      (const __attribute__((address_space(1))) unsigned int*)g,
      (__attribute__((address_space(3))) unsigned int*)l, 16, 0, 0);
}

// One WAVE per row (4 rows/block, no __syncthreads): computes 1/||x|| (fp32),
// writes row normalized*16 as e4m3 via HW cvt, inits the max slot.
__global__ __launch_bounds__(256) void normalize_kernel(
    const float* __restrict__ ex, const float* __restrict__ ey,
    unsigned char* __restrict__ exn, unsigned char* __restrict__ eyn,
    int* __restrict__ rowmax, int* __restrict__ colmax) {
  const int wave = threadIdx.x >> 6, lane = threadIdx.x & 63;
  const int gr = blockIdx.x * 4 + wave;  // 0..16383
  const float* x;
  unsigned char* out;
  int* mslot;
  int row;
  if (gr < N_ROWS) {
    x = ex; out = exn; mslot = rowmax; row = gr;
  } else {
    x = ey; out = eyn; mslot = colmax; row = gr - N_ROWS;
  }
  const float4* xr = (const float4*)(x + (size_t)row * KDIM);
  float4 v[4];
  float ss = 0.f;
#pragma unroll
  for (int j = 0; j < 4; ++j) {
    v[j] = xr[lane + j * 64];  // coalesced
    ss += v[j].x * v[j].x + v[j].y * v[j].y + v[j].z * v[j].z + v[j].w * v[j].w;
  }
#pragma unroll
  for (int off = 32; off > 0; off >>= 1) ss += __shfl_xor(ss, off, 64);
  const float rs = 16.0f * rsqrtf(fmaxf(ss, 1e-24f));  // 2^4 pre-scale
  int* op = (int*)(out + (size_t)row * KDIM);
#pragma unroll
  for (int j = 0; j < 4; ++j) {
    int w = __builtin_amdgcn_cvt_pk_fp8_f32(v[j].x * rs, v[j].y * rs, 0, false);
    w = __builtin_amdgcn_cvt_pk_fp8_f32(v[j].z * rs, v[j].w * rs, w, true);
    op[lane + j * 64] = w;
  }
  if (lane == 0) mslot[row] = (int)0x80000000;  // encoded -inf floor
}

// 256x256 tile GEMM (A @ B^T, row-major K-contiguous e4m3) using MX-scaled
// mfma_scale_f32_32x32x64_f8f6f4, fused with row/col max reduction.
//
// Round-23 change: 8-wave 2x4 grid (per-wave 128x64, acc[4][2]) on the
// fence-free r22 structure. r22 ledger (110 us, best): wall 4125 cy/tile;
// LDS reads 1536 + conflicts 512 + DMA-writes 256 = 2300 (56%, binding);
// MFMA 1104 (27% = measured); VALU ~1100 (addr calc + shufflevector movs
// on the ds_read->MFMA path). The 4x4 wave grid reads each operand 4x;
// 2x4 halves B amplification: 64 -> 48 wave-reads/tile (-25% binding
// pipe) and halves barrier population. This is the guide's 256^2 8-wave
// quadrant -- untested all session because r19/r21 spilled from ASM
// FENCES pinning fragments live (r22 proved fence-free + bF-transient
// stays clean: 64 arch). Fence-free register audit: acc 128 + aF[4] 32 +
// bF 8 + addr ~20 = ~190 <= 256 cap (2 waves/SIMD) -- fits with slack.
// Fragment assembly via union halves (r12 precedent, VALU 16%) instead
// of shufflevector: deletes the mov pairs.
//  - 512 thr, waves: wm=wave>>2 (0..1), wn=wave&3 (0..3).
//  - Staging: 2 DMAs/thread/array (rows tid>>2 and +128; f invariant).
//  - r15/r22 schedule: stage t+1 before COMPUTE(t); one __syncthreads
//    per K-tile; NO inline asm anywhere.
// Data-path bytes identical (same swizzle store/recover; r19 validated
// this epilogue indexing absmax 0.0) -> absmax 0.0 expected.
// Tripwires: WRITE_SIZE ~20 MB (spill -> fence theory wrong, revert to
// r22); clean-but-110 null -> LDS amplification not binding (convoy) ->
// counted phases next.
//
// LDS swizzle (verified r8): 64-B rows, 16-B chunk c of row r at slot
// c ^ ((r>>1)&3); staging pre-swizzles the per-lane global source chunk so
// the linear lane*16 dest lands swizzle-stored; fragment reads recover
// true chunk 2h+j -> operand bytes at (half,j,b) equal global
// k = k0+(2h+j)*16+b for BOTH A and B -> exact dot-product pairing.
// (Dest row = tid>>2 (+128 for DMA1, f(r+128)==f(r)); f(row)=(tid>>3)&3;
// all read-row bases are multiples of 32 -> fsw invariant.)
__global__ __launch_bounds__(512, 1) void gemm_max_kernel(
    const unsigned char* __restrict__ A, const unsigned char* __restrict__ B,
    int* __restrict__ rowmax, int* __restrict__ colmax) {
  constexpr int TM = 256, BK = 64, K = KDIM;
  constexpr int BUF = TM * BK;                          // 16 KB per buffer
  __shared__ __align__(16) unsigned char sA[2 * BUF];   // 32 KB
  __shared__ __align__(16) unsigned char sB[2 * BUF];   // 32 KB

  const int bm = blockIdx.x, bn = blockIdx.y;
  const int tid = threadIdx.x;  // 0..511
  const int lane = tid & 63, wave = tid >> 6;
  const int wm = wave >> 2, wn = wave & 3;  // 2x4 waves of 128x64
  const int l32 = lane & 31, half = lane >> 5;
  const int fsw = (l32 >> 1) & 3;                 // f(row) = (row>>1)&3
  const int oLo = (((2 * half + 0) ^ fsw) << 4);  // swizzled slot offsets
  const int oHi = (((2 * half + 1) ^ fsw) << 4);

  const char* Ab = (const char*)(A + (size_t)bm * TM * K);
  const char* Bb = (const char*)(B + (size_t)bn * TM * K);

  typedef union {
    intx8 v8;
    intx4 v4[2];
  } frag8;

  floatx16 acc[4][2] = {};

  // Staging: 512 lanes stage a 256x64 tile (16 KB) per array in 2 DMAs.
  // DMA0: dest tid*16 -> row tid>>2 (0..127), slot tid&3;
  // DMA1: dest +8192  -> row 128+(tid>>2) (same f since f(r+128)==f(r)).
  // Source chunk = (tid&3) ^ f(row) = (tid&3) ^ ((tid>>3)&3).
  const int src_c16 = (((tid & 3) ^ ((tid >> 3) & 3)) << 4);
  const char* gA = Ab + (size_t)(tid >> 2) * K + src_c16;
  const char* gB = Bb + (size_t)(tid >> 2) * K + src_c16;
  unsigned char* wA = sA + tid * 16;  // linear per-lane dest
  unsigned char* wB = sB + tid * 16;

#define STAGE(k0, buf)                                                      \
  do {                                                                      \
    gld_lds16(gA + (size_t)(k0), wA + (buf)*BUF);                           \
    gld_lds16(gA + (size_t)(k0) + 128 * (size_t)K, wA + (buf)*BUF + 8192);  \
    gld_lds16(gB + (size_t)(k0), wB + (buf)*BUF);                           \
    gld_lds16(gB + (size_t)(k0) + 128 * (size_t)K, wB + (buf)*BUF + 8192);  \
  } while (0)

  // union-half fragment read: two b128 loads land directly in the intx8
  // halves (no shufflevector movs; r12 precedent).
#define RD8(dst, p)                                   \
  do {                                                \
    (dst).v4[0] = *(const intx4*)((p) + oLo);         \
    (dst).v4[1] = *(const intx4*)((p) + oHi);         \
  } while (0)

#define COMPUTE(cur)                                                        \
  do {                                                                      \
    frag8 aF[4];                                                            \
    _Pragma("unroll") for (int mi = 0; mi < 4; ++mi) {                      \
      RD8(aF[mi], &sA[(cur)*BUF + (wm * 128 + mi * 32 + l32) * BK]);        \
    }                                                                       \
    _Pragma("unroll") for (int ni = 0; ni < 2; ++ni) {                      \
      frag8 bF;                                                             \
      RD8(bF, &sB[(cur)*BUF + (wn * 64 + ni * 32 + l32) * BK]);             \
      _Pragma("unroll") for (int mi = 0; mi < 4; ++mi)                      \
          acc[mi][ni] = __builtin_amdgcn_mfma_scale_f32_32x32x64_f8f6f4(    \
              aF[mi].v8, bF.v8, acc[mi][ni], 0, 0, 0, SCALE_WORD, 0,        \
              SCALE_WORD);                                                  \
    }                                                                       \
  } while (0)

  // Prologue: DMA buf0; barrier drains vmcnt(0) -> tile 0 resident.
  STAGE(0, 0);
  __syncthreads();

  // Steady state (r15 schedule): DMA for s+1 (other buffer) issues BEFORE
  // COMPUTE(s); its latency hides under the MFMA phase; the single
  // end-of-step barrier (vmcnt drain) makes it resident for next step.
#pragma unroll 1
  for (int step = 0; step < K / BK - 1; ++step) {
    STAGE((size_t)(step + 1) * BK, (step + 1) & 1);
    COMPUTE(step & 1);
    __syncthreads();
  }
  COMPUTE((K / BK - 1) & 1);

#undef STAGE
#undef RD8
#undef COMPUTE

  // 32x32 C/D layout (m74/m101, dtype-independent):
  //   col = lane&31, row = (reg&3) + 8*(reg>>2) + 4*(lane>>5), reg in [0,16)
  // Row maxes: in-lane over ni, shuffle across 32 cols (masks 1..16 stay
  // within a half), l32==0 lanes write.
#pragma unroll
  for (int mi = 0; mi < 4; ++mi) {
#pragma unroll
    for (int reg = 0; reg < 16; ++reg) {
      float v = fmaxf(acc[mi][0][reg], acc[mi][1][reg]);
#pragma unroll
      for (int m = 1; m < 32; m <<= 1) v = fmaxf(v, __shfl_xor(v, m, 64));
      if (l32 == 0) {
        const int grow = bm * TM + wm * 128 + mi * 32 +
                         (reg & 3) + 8 * (reg >> 2) + 4 * half;
        atomicMax(&rowmax[grow], fenc(v));
      }
    }
  }
  // Col maxes: in-lane over mi,reg (64 vals), combine halves via xor 32.
#pragma unroll
  for (int ni = 0; ni < 2; ++ni) {
    float v = -3.402823466e38f;
#pragma unroll
    for (int mi = 0; mi < 4; ++mi)
#pragma unroll
      for (int reg = 0; reg < 16; ++reg) v = fmaxf(v, acc[mi][ni][reg]);
    v = fmaxf(v, __shfl_xor(v, 32, 64));
    if (half == 0) {
      const int gcol = bn * TM + wn * 64 + ni * 32 + l32;
      atomicMax(&colmax[gcol], fenc(v));
    }
  }
}

__global__ __launch_bounds__(1024) void finalize_kernel(
    const int* __restrict__ rowmax, const int* __restrict__ colmax,
    float* __restrict__ out) {
  const int tid = threadIdx.x;
  float s1 = 0.f, s2 = 0.f;
  for (int i = tid; i < N_ROWS; i += 1024) {
    s1 += 1.0f - fdec(rowmax[i]);
    s2 += 1.0f - fdec(colmax[i]);
  }
#pragma unroll
  for (int off = 32; off > 0; off >>= 1) {
    s1 += __shfl_down(s1, off, 64);
    s2 += __shfl_down(s2, off, 64);
  }
  __shared__ float r1[16], r2[16];
  if ((tid & 63) == 0) {
    r1[tid >> 6] = s1;
    r2[tid >> 6] = s2;
  }
  __syncthreads();
  if (tid == 0) {
    const double SIGMA = 0.3;
    const double H_CONST = 0.5 * log(2.0 * 3.14159265358979323846 * SIGMA * SIGMA) + 0.5;
    const float HS = (float)(H_CONST / SIGMA);
    float a1 = 0.f, a2 = 0.f;
#pragma unroll
    for (int w = 0; w < 16; ++w) {
      a1 += r1[w];
      a2 += r2[w];
    }
    out[0] = HS * a1;
    out[1] = HS * a2;
  }
}

extern "C" void kernel_launch(void* const* d_in, const int* in_sizes, int n_in,
                              void* d_out, int out_size, void* d_ws, size_t ws_size,
                              hipStream_t stream) {
  const float* ex = (const float*)d_in[0];
  const float* ey = (const float*)d_in[1];
  float* out = (float*)d_out;
  char* ws = (char*)d_ws;

  unsigned char* exn = (unsigned char*)ws;                                   // 8 MB
  unsigned char* eyn = (unsigned char*)(ws + (size_t)N_ROWS * KDIM);         // 8 MB
  int* rowmax = (int*)(ws + (size_t)N_ROWS * KDIM * 2);                      // 32 KB
  int* colmax = rowmax + N_ROWS;                                             // 32 KB

  normalize_kernel<<<2 * N_ROWS / 4, 256, 0, stream>>>(ex, ey, exn, eyn, rowmax, colmax);
  gemm_max_kernel<<<dim3(32, 32), 512, 0, stream>>>(exn, eyn, rowmax, colmax);
  finalize_kernel<<<1, 1024, 0, stream>>>(rowmax, colmax, out);
}